// Round 9
// baseline (153.588 us; speedup 1.0000x reference)
//
#include <hip/hip_runtime.h>
#include <hip/hip_bf16.h>

typedef __attribute__((ext_vector_type(8))) short short8;     // 8 bf16 MFMA operand
typedef __attribute__((ext_vector_type(4))) float f32x4;
typedef __attribute__((ext_vector_type(8))) unsigned short ushort8v;

// B=2, T=2048, D_IN=1024, H=16, D_HEAD=64, D_INNER=1024, M=B*T=4096

__device__ __forceinline__ unsigned short f2bf(float f) {
  union { float f; unsigned int u; } x; x.f = f;
  unsigned int r = x.u + 0x7FFFu + ((x.u >> 16) & 1u);   // RNE
  return (unsigned short)(r >> 16);
}

__device__ __forceinline__ unsigned int pk2bf(float lo, float hi) {
  __hip_bfloat162 b2 = __float22bfloat162_rn(make_float2(lo, hi));
  union { __hip_bfloat162 b; unsigned int u; } c; c.b = b2;
  return c.u;
}

__device__ __forceinline__ void gload_lds16(const void* g, void* l) {
  __builtin_amdgcn_global_load_lds(
      (const __attribute__((address_space(1))) void*)g,
      (__attribute__((address_space(3))) void*)l, 16, 0, 0);
}

// ---------------- fused prep: bias_init + x->bf16 + 4 weight transposes ----------------
// grid: [0,4096) cvt x | [4096,7168) Wq/Wk/Wv transpose | [7168,7232) Wo | [7232,7488) bias

__global__ __launch_bounds__(256) void prep(
    const float* __restrict__ x,
    const float* __restrict__ Wq, const float* __restrict__ Wk, const float* __restrict__ Wv,
    const float* __restrict__ Wo, const float* __restrict__ bo,
    unsigned short* __restrict__ xb,
    unsigned short* __restrict__ wqt, unsigned short* __restrict__ wkt,
    unsigned short* __restrict__ wvt, unsigned short* __restrict__ wot,
    float* __restrict__ out) {
  __shared__ float tile[32][33];
  int b = blockIdx.x;
  if (b < 4096) {                     // x -> bf16, 4 elems/thread
    int i = (b * 256 + threadIdx.x) * 4;
    float4 f = *(const float4*)(x + i);
    ushort4 o;
    o.x = f2bf(f.x); o.y = f2bf(f.y); o.z = f2bf(f.z); o.w = f2bf(f.w);
    *(ushort4*)(xb + i) = o;
  } else if (b < 7168) {              // W^T for Wq/Wk/Wv (1024x1024)
    int idx = b - 4096;
    int z = idx >> 10, rem = idx & 1023;
    const float* src = (z == 0) ? Wq : (z == 1) ? Wk : Wv;
    unsigned short* dst = (z == 0) ? wqt : (z == 1) ? wkt : wvt;
    int kx = (rem & 31) * 32, ny = (rem >> 5) * 32;
    int tx = threadIdx.x & 31, ty = threadIdx.x >> 5;
    #pragma unroll
    for (int r = 0; r < 32; r += 8)
      tile[ty + r][tx] = src[(size_t)(kx + ty + r) * 1024 + ny + tx];
    __syncthreads();
    #pragma unroll
    for (int r = 0; r < 32; r += 8)
      dst[(size_t)(ny + ty + r) * 1024 + kx + tx] = f2bf(tile[tx][ty + r]);
  } else if (b < 7232) {              // Wo^T (1024x64 -> 64x1024)
    int idx = b - 7168;
    int kx = (idx & 31) * 32, ny = (idx >> 5) * 32;
    int tx = threadIdx.x & 31, ty = threadIdx.x >> 5;
    #pragma unroll
    for (int r = 0; r < 32; r += 8)
      tile[ty + r][tx] = Wo[(size_t)(kx + ty + r) * 64 + ny + tx];
    __syncthreads();
    #pragma unroll
    for (int r = 0; r < 32; r += 8)
      wot[(size_t)(ny + ty + r) * 1024 + kx + tx] = f2bf(tile[tx][ty + r]);
  } else {                            // seed out with bias (out is re-poisoned each call)
    int t = (b - 7232) * 256 + threadIdx.x;  // 65536 float4s
    float4 bi = *(const float4*)(bo + (t & 15) * 4);
    *(float4*)(out + (size_t)t * 4) = bi;
  }
}

// ---------------- QKV projection GEMM v4: 128^2 tile, DEPTH-2 counted pipeline ----------------
// v3 post-mortem: vmcnt(0)/iter = 1-deep prefetch; loads got ~1 compute phase (<L2
// latency) -> exposed wait every iter (36us, 716 TF). v4: 3-slot rotation, vmcnt(4):
// tile i+1's 4 loads STAY IN FLIGHT across the wait; loads get 2 compute phases
// (~400cyc >= L2 ~200). LDS 3x16KB=48KB -> exactly 3 blocks/CU (launch_bounds(256,3)),
// grid 768 = 256x3 all-resident. Per iter:
//   { vmcnt(4) [tile i landed; i+1 in flight]  (last iter: vmcnt(0));
//     s_barrier [each wave certified OWN tile-i loads -> all visible];
//     stage tile i+2 -> slot (i+2)%3 [last read iter i-1, certified by barrier];
//     8 ds_read_b128 + 16 MFMA on slot i%3 }
// Swizzle s(row)=((row>>1)&3) -> exact 2-way (free). XCD swizzle bijective (768%8==0).
// Q scale folds 1/32*log2e.

__global__ __launch_bounds__(256, 3) void qkv_gemm4(
    const unsigned short* __restrict__ Xb,
    const unsigned short* __restrict__ Wstk,
    unsigned short* __restrict__ Oq, unsigned short* __restrict__ Ok,
    unsigned short* __restrict__ Ovt) {
  constexpr int Kd = 1024, BK = 32, NT = Kd / BK;  // 32 k-tiles
  __shared__ __align__(16) unsigned short As[3][128 * 32];
  __shared__ __align__(16) unsigned short Bs[3][128 * 32];

  int wg = blockIdx.x;                       // 768 = 24 m-tiles x 32 n-tiles
  int swz8 = (wg & 7) * 96 + (wg >> 3);      // bijective XCD swizzle (cpx=96)
  int mt = swz8 >> 5, ntile = swz8 & 31;     // ntile fastest: same-XCD neighbors share A
  int m0 = mt * 128, n0 = ntile * 128;

  int tid = threadIdx.x, lane = tid & 63, wave = tid >> 6;
  int wm = wave >> 1, wn = wave & 1;         // 2x2 wave grid; per-wave C = 64x64
  int l15 = lane & 15, quad = lane >> 4;

  // staging: i = tid, tid+256 -> row = i>>2 (0..127), granule g = i&3.
  // global granule = g ^ ((row>>1)&3); LDS dest linear i*16B.
  int sr0 = tid >> 2, sg0 = tid & 3;
  int sr1 = (tid + 256) >> 2, sg1 = (tid + 256) & 3;
  int ga0 = (sg0 ^ ((sr0 >> 1) & 3)) * 8, ga1 = (sg1 ^ ((sr1 >> 1) & 3)) * 8;

  f32x4 acc[4][4] = {};

  // prologue: stage tiles 0,1 into slots 0,1 (8 loads outstanding)
  gload_lds16(Wstk + (size_t)(m0 + sr0) * Kd + ga0, &As[0][tid * 8]);
  gload_lds16(Wstk + (size_t)(m0 + sr1) * Kd + ga1, &As[0][(tid + 256) * 8]);
  gload_lds16(Xb + (size_t)(n0 + sr0) * Kd + ga0, &Bs[0][tid * 8]);
  gload_lds16(Xb + (size_t)(n0 + sr1) * Kd + ga1, &Bs[0][(tid + 256) * 8]);
  gload_lds16(Wstk + (size_t)(m0 + sr0) * Kd + BK + ga0, &As[1][tid * 8]);
  gload_lds16(Wstk + (size_t)(m0 + sr1) * Kd + BK + ga1, &As[1][(tid + 256) * 8]);
  gload_lds16(Xb + (size_t)(n0 + sr0) * Kd + BK + ga0, &Bs[1][tid * 8]);
  gload_lds16(Xb + (size_t)(n0 + sr1) * Kd + BK + ga1, &Bs[1][(tid + 256) * 8]);

  int cur = 0;
  for (int i = 0; i < NT; ++i) {
    if (i < NT - 1) { asm volatile("s_waitcnt vmcnt(4)" ::: "memory"); }  // tile i landed; i+1 in flight
    else            { asm volatile("s_waitcnt vmcnt(0)" ::: "memory"); }
    __builtin_amdgcn_s_barrier();                      // all waves' tile i visible
    __builtin_amdgcn_sched_barrier(0);

    if (i + 2 < NT) {                                  // stage tile i+2 -> slot (i+2)%3
      int s2 = cur + 2; if (s2 >= 3) s2 -= 3;
      int k0 = (i + 2) * BK;
      gload_lds16(Wstk + (size_t)(m0 + sr0) * Kd + k0 + ga0, &As[s2][tid * 8]);
      gload_lds16(Wstk + (size_t)(m0 + sr1) * Kd + k0 + ga1, &As[s2][(tid + 256) * 8]);
      gload_lds16(Xb + (size_t)(n0 + sr0) * Kd + k0 + ga0, &Bs[s2][tid * 8]);
      gload_lds16(Xb + (size_t)(n0 + sr1) * Kd + k0 + ga1, &Bs[s2][(tid + 256) * 8]);
    }

    // compute tile i from slot cur: 8 ds_read_b128 + 16 MFMA
    {
      const unsigned short* Ab = As[cur];
      const unsigned short* Bb = Bs[cur];
      short8 bfr[4];
      #pragma unroll
      for (int ni = 0; ni < 4; ++ni) {
        int row = wn * 64 + ni * 16 + l15;
        bfr[ni] = *(const short8*)&Bb[row * 32 + ((quad ^ ((row >> 1) & 3)) * 8)];
      }
      __builtin_amdgcn_s_setprio(1);
      #pragma unroll
      for (int mi = 0; mi < 4; ++mi) {
        int row = wm * 64 + mi * 16 + l15;
        short8 af = *(const short8*)&Ab[row * 32 + ((quad ^ ((row >> 1) & 3)) * 8)];
        #pragma unroll
        for (int ni = 0; ni < 4; ++ni)
          acc[mi][ni] = __builtin_amdgcn_mfma_f32_16x16x32_bf16(af, bfr[ni], acc[mi][ni], 0, 0, 0);
      }
      __builtin_amdgcn_s_setprio(0);
    }
    if (++cur == 3) cur = 0;
  }

  // epilogue: region by m (mt 0-7 q, 8-15 k, 16-23 v); per-lane rows = 4 consecutive d
  int region = mt >> 3;
  if (region < 2) {
    unsigned short* O = (region == 0) ? Oq : Ok;
    float scale = (region == 0) ? 0.0450842200f : 1.0f;  // 1/sqrt(1024)*log2(e) for Q
    #pragma unroll
    for (int mi = 0; mi < 4; ++mi) {
      int dg = (m0 - region * 1024) + wm * 64 + mi * 16 + quad * 4;
      int h = dg >> 6, d0 = dg & 63;
      #pragma unroll
      for (int ni = 0; ni < 4; ++ni) {
        int t = n0 + wn * 64 + ni * 16 + l15;
        int b = t >> 11, tt = t & 2047;
        uint2 pk;
        pk.x = pk2bf(acc[mi][ni][0] * scale, acc[mi][ni][1] * scale);
        pk.y = pk2bf(acc[mi][ni][2] * scale, acc[mi][ni][3] * scale);
        *(uint2*)(O + (((size_t)(b * 16 + h) * 2048 + tt) << 6) + d0) = pk;
      }
    }
  } else {
    #pragma unroll
    for (int mi = 0; mi < 4; ++mi) {
      int dg = (m0 - 2048) + wm * 64 + mi * 16 + quad * 4;
      int h = dg >> 6, d0 = dg & 63;
      #pragma unroll
      for (int ni = 0; ni < 4; ++ni) {
        int t = n0 + wn * 64 + ni * 16 + l15;
        int b = t >> 11, tt = t & 2047;
        #pragma unroll
        for (int r = 0; r < 4; ++r)
          Ovt[(((size_t)(b * 16 + h) * 64 + d0 + r) << 11) + tt] = f2bf(acc[mi][ni][r]);
      }
    }
  }
}

// ---------------- fused causal flash attention v13 = v11 loop + fused out-proj ----------------
// Main loop EXACTLY v11 (best measured 46.1us). Epilogue: out-projection fused per
// (b,h,q-tile) block: normalize Oacc -> bf16 into this wave's OWN Ps slot (zero barriers),
// 8 Wo^T B-frags (L2-hot), 8 MFMAs, 16 f32 atomicAdds/lane onto bias-seeded out.

__global__ __launch_bounds__(256, 4) void attn13(
    const unsigned short* __restrict__ Qg, const unsigned short* __restrict__ Kg,
    const unsigned short* __restrict__ Vtg, const unsigned short* __restrict__ Wot,
    float* __restrict__ out) {
  constexpr int T = 2048;
  __shared__ __align__(16) unsigned short Ks[2][64 * 64];   // [tok][d], XOR-swz
  __shared__ __align__(16) unsigned short Vs[2][64 * 64];   // [d][tok], XOR-swz
  __shared__ __align__(16) unsigned short Ps[4][16 * 64];   // per-wave, XOR-swz
  int bh = blockIdx.x;
  int by = blockIdx.y;
  int g = by >> 3, w8 = by & 7;
  int qt = (g == 0) ? w8 : (g == 1) ? (15 - w8) : (g == 2) ? (16 + w8) : (31 - w8);
  int tid = threadIdx.x, lane = tid & 63, wave = tid >> 6;
  int l15 = lane & 15, quad = lane >> 4;
  int swz = l15 & 7;
  const unsigned short* Qb = Qg + (size_t)bh * T * 64;
  const unsigned short* Kb = Kg + (size_t)bh * T * 64;
  const unsigned short* Vb = Vtg + (size_t)bh * 64 * T;
  int h = bh & 15, b = bh >> 4;
  int qw = qt * 64 + wave * 16;

  short8 qf[2];
  #pragma unroll
  for (int s = 0; s < 2; ++s)
    qf[s] = *(const short8*)(Qb + (size_t)(qw + l15) * 64 + quad * 8 + 32 * s);

  f32x4 Oacc[4] = {};
  float m_run = -__builtin_inff();
  float l_run = 0.f;

  int srow = tid >> 3, sc8 = tid & 7;
  int sdst = srow * 64 + ((sc8 ^ (srow & 7)) * 8);

  ushort8v kpre[2], vpre[2];
  #pragma unroll
  for (int r = 0; r < 2; ++r) {
    kpre[r] = *(const ushort8v*)(Kb + (size_t)(srow + 32 * r) * 64 + sc8 * 8);
    vpre[r] = *(const ushort8v*)(Vb + (size_t)(srow + 32 * r) * T + sc8 * 8);
  }
  *(ushort8v*)&Ks[0][sdst] = kpre[0];
  *(ushort8v*)&Ks[0][sdst + 2048] = kpre[1];
  *(ushort8v*)&Vs[0][sdst] = vpre[0];
  *(ushort8v*)&Vs[0][sdst + 2048] = vpre[1];
  __syncthreads();

  for (int kt = 0; kt <= qt; ++kt) {
    const unsigned short* Kl = Ks[kt & 1];
    const unsigned short* Vl = Vs[kt & 1];
    unsigned short* Kn = Ks[(kt & 1) ^ 1];
    unsigned short* Vn = Vs[(kt & 1) ^ 1];

    if (kt < qt) {
      #pragma unroll
      for (int r = 0; r < 2; ++r) {
        kpre[r] = *(const ushort8v*)(Kb + (size_t)((kt + 1) * 64 + srow + 32 * r) * 64 + sc8 * 8);
        vpre[r] = *(const ushort8v*)(Vb + (size_t)(srow + 32 * r) * T + (kt + 1) * 64 + sc8 * 8);
      }
    }

    f32x4 S[4] = {};
    __builtin_amdgcn_s_setprio(1);
    #pragma unroll
    for (int s = 0; s < 2; ++s)
      #pragma unroll
      for (int mi = 0; mi < 4; ++mi) {
        short8 kf = *(const short8*)&Kl[(mi * 16 + l15) * 64 + ((quad + 4 * s) ^ swz) * 8];
        S[mi] = __builtin_amdgcn_mfma_f32_16x16x32_bf16(kf, qf[s], S[mi], 0, 0, 0);
      }
    __builtin_amdgcn_s_setprio(0);

    if (kt == qt) {  // diagonal tile: causal mask
      int ql = wave * 16 + l15;
      #pragma unroll
      for (int mi = 0; mi < 4; ++mi) {
        int tokl = mi * 16 + quad * 4;
        #pragma unroll
        for (int r = 0; r < 4; ++r)
          if (tokl + r > ql) S[mi][r] = -__builtin_inff();
      }
    }

    float t0 = fmaxf(fmaxf(S[0][0], S[0][1]), fmaxf(S[0][2], S[0][3]));
    float t1 = fmaxf(fmaxf(S[1][0], S[1][1]), fmaxf(S[1][2], S[1][3]));
    float t2 = fmaxf(fmaxf(S[2][0], S[2][1]), fmaxf(S[2][2], S[2][3]));
    float t3 = fmaxf(fmaxf(S[3][0], S[3][1]), fmaxf(S[3][2], S[3][3]));
    float vmax = fmaxf(fmaxf(t0, t1), fmaxf(t2, t3));
    vmax = fmaxf(vmax, __shfl_xor(vmax, 16));
    vmax = fmaxf(vmax, __shfl_xor(vmax, 32));
    float mold = m_run;
    bool defer = __all(vmax - mold <= 8.f) != 0;   // mold=-inf -> false
    float mnew = defer ? mold : fmaxf(mold, vmax);
    float alpha = defer ? 1.f : __builtin_amdgcn_exp2f(mold - mnew);
    m_run = mnew;
    float rs = 0.f;
    #pragma unroll
    for (int mi = 0; mi < 4; ++mi) {
      float p0 = __builtin_amdgcn_exp2f(S[mi][0] - mnew);
      float p1 = __builtin_amdgcn_exp2f(S[mi][1] - mnew);
      float p2 = __builtin_amdgcn_exp2f(S[mi][2] - mnew);
      float p3 = __builtin_amdgcn_exp2f(S[mi][3] - mnew);
      rs += (p0 + p1) + (p2 + p3);
      uint2 pk;
      pk.x = pk2bf(p0, p1);
      pk.y = pk2bf(p2, p3);
      int gg = (2 * mi + (quad >> 1)) ^ swz;
      *(uint2*)&Ps[wave][l15 * 64 + gg * 8 + (quad & 1) * 4] = pk;
    }
    rs += __shfl_xor(rs, 16);
    rs += __shfl_xor(rs, 32);
    l_run = l_run * alpha + rs;

    if (!defer)
      #pragma unroll
      for (int jd = 0; jd < 4; ++jd)
        #pragma unroll
        for (int r = 0; r < 4; ++r)
          Oacc[jd][r] *= alpha;

    if (kt < qt) {
      *(ushort8v*)&Kn[sdst] = kpre[0];
      *(ushort8v*)&Kn[sdst + 2048] = kpre[1];
      *(ushort8v*)&Vn[sdst] = vpre[0];
      *(ushort8v*)&Vn[sdst + 2048] = vpre[1];
    }

    __builtin_amdgcn_s_setprio(1);
    #pragma unroll
    for (int s = 0; s < 2; ++s) {
      short8 pf = *(const short8*)&Ps[wave][l15 * 64 + ((quad + 4 * s) ^ swz) * 8];
      #pragma unroll
      for (int jd = 0; jd < 4; ++jd) {
        short8 vfr = *(const short8*)&Vl[(jd * 16 + l15) * 64 + ((quad + 4 * s) ^ swz) * 8];
        Oacc[jd] = __builtin_amdgcn_mfma_f32_16x16x32_bf16(vfr, pf, Oacc[jd], 0, 0, 0);
      }
    }
    __builtin_amdgcn_s_setprio(0);
    if (kt < qt) __syncthreads();
  }

  // ---- fused out-projection epilogue (no barriers: each wave uses only its own Ps slot) ----
  {
    float linv = 1.f / l_run;
    unsigned short* Yl = &Ps[wave][0];
    #pragma unroll
    for (int jd = 0; jd < 4; ++jd) {
      uint2 pk;
      pk.x = pk2bf(Oacc[jd][0] * linv, Oacc[jd][1] * linv);
      pk.y = pk2bf(Oacc[jd][2] * linv, Oacc[jd][3] * linv);
      int gg = (jd * 2 + (quad >> 1)) ^ swz;
      *(uint2*)&Yl[l15 * 64 + gg * 8 + (quad & 1) * 4] = pk;
    }
    short8 wof[4][2];
    #pragma unroll
    for (int nt = 0; nt < 4; ++nt)
      #pragma unroll
      for (int s = 0; s < 2; ++s)
        wof[nt][s] = *(const short8*)(Wot + (size_t)(nt * 16 + l15) * 1024 + h * 64 + quad * 8 + 32 * s);
    f32x4 acc2[4] = {};
    #pragma unroll
    for (int s = 0; s < 2; ++s) {
      short8 ya = *(const short8*)&Yl[l15 * 64 + (((quad + 4 * s) ^ swz) * 8)];
      #pragma unroll
      for (int nt = 0; nt < 4; ++nt)
        acc2[nt] = __builtin_amdgcn_mfma_f32_16x16x32_bf16(ya, wof[nt][s], acc2[nt], 0, 0, 0);
    }
    int q0 = b * 2048 + qt * 64 + wave * 16 + quad * 4;
    #pragma unroll
    for (int nt = 0; nt < 4; ++nt)
      #pragma unroll
      for (int r = 0; r < 4; ++r)
        atomicAdd(&out[(size_t)(q0 + r) * 64 + nt * 16 + l15], acc2[nt][r]);
  }
}

// ---------------- launcher (3 kernels total) ----------------

extern "C" void kernel_launch(void* const* d_in, const int* in_sizes, int n_in,
                              void* d_out, int out_size, void* d_ws, size_t ws_size,
                              hipStream_t stream) {
  const float* x  = (const float*)d_in[0];
  const float* Wq = (const float*)d_in[1];
  const float* Wk = (const float*)d_in[2];
  const float* Wv = (const float*)d_in[3];
  const float* Wo = (const float*)d_in[4];
  const float* bo = (const float*)d_in[5];
  float* out = (float*)d_out;
  char* ws = (char*)d_ws;

  unsigned short* xb  = (unsigned short*)(ws);                       // 8 MB  [4096][1024]
  unsigned short* wqt = (unsigned short*)(ws + (8ull << 20));        // 2 MB Wq^T (head of contiguous [3072][1024] W-stack)
  unsigned short* wkt = (unsigned short*)(ws + (10ull << 20));       // 2 MB Wk^T (stack middle)
  unsigned short* wvt = (unsigned short*)(ws + (12ull << 20));       // 2 MB Wv^T (stack tail)
  unsigned short* wot = (unsigned short*)(ws + (14ull << 20));       // 128 KB Wo^T
  unsigned short* q   = (unsigned short*)(ws + (15ull << 20));       // 8 MB  [b][h][t][d]
  unsigned short* k   = (unsigned short*)(ws + (23ull << 20));       // 8 MB  [b][h][t][d]
  unsigned short* vt  = (unsigned short*)(ws + (31ull << 20));       // 8 MB  [b][h][d][t]

  prep<<<7488, 256, 0, stream>>>(x, Wq, Wk, Wv, Wo, bo, xb, wqt, wkt, wvt, wot, out);
  qkv_gemm4<<<768, 256, 0, stream>>>(xb, wqt, q, k, vt);
  attn13<<<dim3(32, 32), 256, 0, stream>>>(q, k, vt, wot, out);
}

// Round 10
// 149.392 us; speedup vs baseline: 1.0281x; 1.0281x over previous
//
#include <hip/hip_runtime.h>
#include <hip/hip_bf16.h>

typedef __attribute__((ext_vector_type(8))) short short8;     // 8 bf16 MFMA operand
typedef __attribute__((ext_vector_type(4))) float f32x4;
typedef __attribute__((ext_vector_type(8))) unsigned short ushort8v;

// B=2, T=2048, D_IN=1024, H=16, D_HEAD=64, D_INNER=1024, M=B*T=4096

__device__ __forceinline__ unsigned short f2bf(float f) {
  union { float f; unsigned int u; } x; x.f = f;
  unsigned int r = x.u + 0x7FFFu + ((x.u >> 16) & 1u);   // RNE
  return (unsigned short)(r >> 16);
}

__device__ __forceinline__ unsigned int pk2bf(float lo, float hi) {
  __hip_bfloat162 b2 = __float22bfloat162_rn(make_float2(lo, hi));
  union { __hip_bfloat162 b; unsigned int u; } c; c.b = b2;
  return c.u;
}

__device__ __forceinline__ void gload_lds16(const void* g, void* l) {
  __builtin_amdgcn_global_load_lds(
      (const __attribute__((address_space(1))) void*)g,
      (__attribute__((address_space(3))) void*)l, 16, 0, 0);
}

// ---------------- fused prep: bias_init + x->bf16 + 4 weight transposes ----------------
// grid: [0,4096) cvt x | [4096,7168) Wq/Wk/Wv transpose | [7168,7232) Wo | [7232,7488) bias

__global__ __launch_bounds__(256) void prep(
    const float* __restrict__ x,
    const float* __restrict__ Wq, const float* __restrict__ Wk, const float* __restrict__ Wv,
    const float* __restrict__ Wo, const float* __restrict__ bo,
    unsigned short* __restrict__ xb,
    unsigned short* __restrict__ wqt, unsigned short* __restrict__ wkt,
    unsigned short* __restrict__ wvt, unsigned short* __restrict__ wot,
    float* __restrict__ out) {
  __shared__ float tile[32][33];
  int b = blockIdx.x;
  if (b < 4096) {                     // x -> bf16, 4 elems/thread
    int i = (b * 256 + threadIdx.x) * 4;
    float4 f = *(const float4*)(x + i);
    ushort4 o;
    o.x = f2bf(f.x); o.y = f2bf(f.y); o.z = f2bf(f.z); o.w = f2bf(f.w);
    *(ushort4*)(xb + i) = o;
  } else if (b < 7168) {              // W^T for Wq/Wk/Wv (1024x1024)
    int idx = b - 4096;
    int z = idx >> 10, rem = idx & 1023;
    const float* src = (z == 0) ? Wq : (z == 1) ? Wk : Wv;
    unsigned short* dst = (z == 0) ? wqt : (z == 1) ? wkt : wvt;
    int kx = (rem & 31) * 32, ny = (rem >> 5) * 32;
    int tx = threadIdx.x & 31, ty = threadIdx.x >> 5;
    #pragma unroll
    for (int r = 0; r < 32; r += 8)
      tile[ty + r][tx] = src[(size_t)(kx + ty + r) * 1024 + ny + tx];
    __syncthreads();
    #pragma unroll
    for (int r = 0; r < 32; r += 8)
      dst[(size_t)(ny + ty + r) * 1024 + kx + tx] = f2bf(tile[tx][ty + r]);
  } else if (b < 7232) {              // Wo^T (1024x64 -> 64x1024)
    int idx = b - 7168;
    int kx = (idx & 31) * 32, ny = (idx >> 5) * 32;
    int tx = threadIdx.x & 31, ty = threadIdx.x >> 5;
    #pragma unroll
    for (int r = 0; r < 32; r += 8)
      tile[ty + r][tx] = Wo[(size_t)(kx + ty + r) * 64 + ny + tx];
    __syncthreads();
    #pragma unroll
    for (int r = 0; r < 32; r += 8)
      wot[(size_t)(ny + ty + r) * 1024 + kx + tx] = f2bf(tile[tx][ty + r]);
  } else {                            // seed out with bias (out is re-poisoned each call)
    int t = (b - 7232) * 256 + threadIdx.x;  // 65536 float4s
    float4 bi = *(const float4*)(bo + (t & 15) * 4);
    *(float4*)(out + (size_t)t * 4) = bi;
  }
}

// ---------------- QKV projection GEMM v3 (reverted best: 152.4us config) ----------------
// 128^2 tile, BK=32, 2-slot counted pipeline, 4 blocks/CU, grid 768.
// v4's depth-2 (3-slot, vmcnt(4), 3 blocks/CU) was neutral: latency cover bought
// with occupancy. Keep v3.

__global__ __launch_bounds__(256, 4) void qkv_gemm3(
    const unsigned short* __restrict__ Xb,
    const unsigned short* __restrict__ Wstk,
    unsigned short* __restrict__ Oq, unsigned short* __restrict__ Ok,
    unsigned short* __restrict__ Ovt) {
  constexpr int Kd = 1024, BK = 32, NT = Kd / BK;  // 32 k-tiles
  __shared__ __align__(16) unsigned short As[2][128 * 32];
  __shared__ __align__(16) unsigned short Bs[2][128 * 32];

  int wg = blockIdx.x;                       // 768 = 24 m-tiles x 32 n-tiles
  int swz8 = (wg & 7) * 96 + (wg >> 3);      // bijective XCD swizzle (cpx=96)
  int mt = swz8 >> 5, ntile = swz8 & 31;     // ntile fastest: same-XCD neighbors share A
  int m0 = mt * 128, n0 = ntile * 128;

  int tid = threadIdx.x, lane = tid & 63, wave = tid >> 6;
  int wm = wave >> 1, wn = wave & 1;         // 2x2 wave grid; per-wave C = 64x64
  int l15 = lane & 15, quad = lane >> 4;

  // staging: i = tid, tid+256 -> row = i>>2 (0..127), granule g = i&3.
  // global granule = g ^ ((row>>1)&3); LDS dest linear i*16B.
  int sr0 = tid >> 2, sg0 = tid & 3;
  int sr1 = (tid + 256) >> 2, sg1 = (tid + 256) & 3;
  int ga0 = (sg0 ^ ((sr0 >> 1) & 3)) * 8, ga1 = (sg1 ^ ((sr1 >> 1) & 3)) * 8;

  f32x4 acc[4][4] = {};

  // prologue: stage tile 0 into slot 0
  gload_lds16(Wstk + (size_t)(m0 + sr0) * Kd + ga0, &As[0][tid * 8]);
  gload_lds16(Wstk + (size_t)(m0 + sr1) * Kd + ga1, &As[0][(tid + 256) * 8]);
  gload_lds16(Xb + (size_t)(n0 + sr0) * Kd + ga0, &Bs[0][tid * 8]);
  gload_lds16(Xb + (size_t)(n0 + sr1) * Kd + ga1, &Bs[0][(tid + 256) * 8]);

  for (int i = 0; i < NT; ++i) {
    int cur = i & 1;
    asm volatile("s_waitcnt vmcnt(0)" ::: "memory");   // tile i landed (mine)
    __builtin_amdgcn_s_barrier();                      // all waves' tile i visible
    __builtin_amdgcn_sched_barrier(0);

    if (i + 1 < NT) {                                  // stage tile i+1 -> other slot
      int k0 = (i + 1) * BK;
      gload_lds16(Wstk + (size_t)(m0 + sr0) * Kd + k0 + ga0, &As[cur ^ 1][tid * 8]);
      gload_lds16(Wstk + (size_t)(m0 + sr1) * Kd + k0 + ga1, &As[cur ^ 1][(tid + 256) * 8]);
      gload_lds16(Xb + (size_t)(n0 + sr0) * Kd + k0 + ga0, &Bs[cur ^ 1][tid * 8]);
      gload_lds16(Xb + (size_t)(n0 + sr1) * Kd + k0 + ga1, &Bs[cur ^ 1][(tid + 256) * 8]);
    }

    // compute tile i from slot cur: 8 ds_read_b128 + 16 MFMA
    {
      const unsigned short* Ab = As[cur];
      const unsigned short* Bb = Bs[cur];
      short8 bfr[4];
      #pragma unroll
      for (int ni = 0; ni < 4; ++ni) {
        int row = wn * 64 + ni * 16 + l15;
        bfr[ni] = *(const short8*)&Bb[row * 32 + ((quad ^ ((row >> 1) & 3)) * 8)];
      }
      __builtin_amdgcn_s_setprio(1);
      #pragma unroll
      for (int mi = 0; mi < 4; ++mi) {
        int row = wm * 64 + mi * 16 + l15;
        short8 af = *(const short8*)&Ab[row * 32 + ((quad ^ ((row >> 1) & 3)) * 8)];
        #pragma unroll
        for (int ni = 0; ni < 4; ++ni)
          acc[mi][ni] = __builtin_amdgcn_mfma_f32_16x16x32_bf16(af, bfr[ni], acc[mi][ni], 0, 0, 0);
      }
      __builtin_amdgcn_s_setprio(0);
    }
  }

  // epilogue: region by m (mt 0-7 q, 8-15 k, 16-23 v); per-lane rows = 4 consecutive d
  int region = mt >> 3;
  if (region < 2) {
    unsigned short* O = (region == 0) ? Oq : Ok;
    float scale = (region == 0) ? 0.0450842200f : 1.0f;  // 1/sqrt(1024)*log2(e) for Q
    #pragma unroll
    for (int mi = 0; mi < 4; ++mi) {
      int dg = (m0 - region * 1024) + wm * 64 + mi * 16 + quad * 4;
      int h = dg >> 6, d0 = dg & 63;
      #pragma unroll
      for (int ni = 0; ni < 4; ++ni) {
        int t = n0 + wn * 64 + ni * 16 + l15;
        int b = t >> 11, tt = t & 2047;
        uint2 pk;
        pk.x = pk2bf(acc[mi][ni][0] * scale, acc[mi][ni][1] * scale);
        pk.y = pk2bf(acc[mi][ni][2] * scale, acc[mi][ni][3] * scale);
        *(uint2*)(O + (((size_t)(b * 16 + h) * 2048 + tt) << 6) + d0) = pk;
      }
    }
  } else {
    #pragma unroll
    for (int mi = 0; mi < 4; ++mi) {
      int dg = (m0 - 2048) + wm * 64 + mi * 16 + quad * 4;
      int h = dg >> 6, d0 = dg & 63;
      #pragma unroll
      for (int ni = 0; ni < 4; ++ni) {
        int t = n0 + wn * 64 + ni * 16 + l15;
        int b = t >> 11, tt = t & 2047;
        #pragma unroll
        for (int r = 0; r < 4; ++r)
          Ovt[(((size_t)(b * 16 + h) * 64 + d0 + r) << 11) + tt] = f2bf(acc[mi][ni][r]);
      }
    }
  }
}

// ---------------- fused causal flash attention v14: shuffle-light softmax ----------------
// vs v13: the per-iter chain had 4 __shfl_xor LDS round-trips (~160-240cyc of ~1500).
// (1) Defer-check FIRST on per-lane max: __all(vmax_loc - m_old <= 8) is equivalent
//     to checking the reduced max. When defer (almost every tile), SKIP both max
//     shuffles, keep m_old, alpha=1. Wave-uniform branch (__all).
// (2) l_run kept as per-lane PARTIAL (alpha is quad-uniform); the 2 sum shuffles
//     move to the epilogue, once. f32-order change negligible vs bf16 quantum.
// Common path: 0 shuffles/iter (was 4). Rest identical to v13 (XOR-swz LDS, dbuf
// write-late, exp2 domain, setprio, fused out-proj epilogue).

__global__ __launch_bounds__(256, 4) void attn14(
    const unsigned short* __restrict__ Qg, const unsigned short* __restrict__ Kg,
    const unsigned short* __restrict__ Vtg, const unsigned short* __restrict__ Wot,
    float* __restrict__ out) {
  constexpr int T = 2048;
  __shared__ __align__(16) unsigned short Ks[2][64 * 64];   // [tok][d], XOR-swz
  __shared__ __align__(16) unsigned short Vs[2][64 * 64];   // [d][tok], XOR-swz
  __shared__ __align__(16) unsigned short Ps[4][16 * 64];   // per-wave, XOR-swz
  int bh = blockIdx.x;
  int by = blockIdx.y;
  int g = by >> 3, w8 = by & 7;
  int qt = (g == 0) ? w8 : (g == 1) ? (15 - w8) : (g == 2) ? (16 + w8) : (31 - w8);
  int tid = threadIdx.x, lane = tid & 63, wave = tid >> 6;
  int l15 = lane & 15, quad = lane >> 4;
  int swz = l15 & 7;
  const unsigned short* Qb = Qg + (size_t)bh * T * 64;
  const unsigned short* Kb = Kg + (size_t)bh * T * 64;
  const unsigned short* Vb = Vtg + (size_t)bh * 64 * T;
  int h = bh & 15, b = bh >> 4;
  int qw = qt * 64 + wave * 16;

  short8 qf[2];
  #pragma unroll
  for (int s = 0; s < 2; ++s)
    qf[s] = *(const short8*)(Qb + (size_t)(qw + l15) * 64 + quad * 8 + 32 * s);

  f32x4 Oacc[4] = {};
  float m_run = -__builtin_inff();
  float l_part = 0.f;                      // per-lane partial denominator

  int srow = tid >> 3, sc8 = tid & 7;
  int sdst = srow * 64 + ((sc8 ^ (srow & 7)) * 8);

  ushort8v kpre[2], vpre[2];
  #pragma unroll
  for (int r = 0; r < 2; ++r) {
    kpre[r] = *(const ushort8v*)(Kb + (size_t)(srow + 32 * r) * 64 + sc8 * 8);
    vpre[r] = *(const ushort8v*)(Vb + (size_t)(srow + 32 * r) * T + sc8 * 8);
  }
  *(ushort8v*)&Ks[0][sdst] = kpre[0];
  *(ushort8v*)&Ks[0][sdst + 2048] = kpre[1];
  *(ushort8v*)&Vs[0][sdst] = vpre[0];
  *(ushort8v*)&Vs[0][sdst + 2048] = vpre[1];
  __syncthreads();

  for (int kt = 0; kt <= qt; ++kt) {
    const unsigned short* Kl = Ks[kt & 1];
    const unsigned short* Vl = Vs[kt & 1];
    unsigned short* Kn = Ks[(kt & 1) ^ 1];
    unsigned short* Vn = Vs[(kt & 1) ^ 1];

    if (kt < qt) {
      #pragma unroll
      for (int r = 0; r < 2; ++r) {
        kpre[r] = *(const ushort8v*)(Kb + (size_t)((kt + 1) * 64 + srow + 32 * r) * 64 + sc8 * 8);
        vpre[r] = *(const ushort8v*)(Vb + (size_t)(srow + 32 * r) * T + (kt + 1) * 64 + sc8 * 8);
      }
    }

    f32x4 S[4] = {};
    __builtin_amdgcn_s_setprio(1);
    #pragma unroll
    for (int s = 0; s < 2; ++s)
      #pragma unroll
      for (int mi = 0; mi < 4; ++mi) {
        short8 kf = *(const short8*)&Kl[(mi * 16 + l15) * 64 + ((quad + 4 * s) ^ swz) * 8];
        S[mi] = __builtin_amdgcn_mfma_f32_16x16x32_bf16(kf, qf[s], S[mi], 0, 0, 0);
      }
    __builtin_amdgcn_s_setprio(0);

    if (kt == qt) {  // diagonal tile: causal mask
      int ql = wave * 16 + l15;
      #pragma unroll
      for (int mi = 0; mi < 4; ++mi) {
        int tokl = mi * 16 + quad * 4;
        #pragma unroll
        for (int r = 0; r < 4; ++r)
          if (tokl + r > ql) S[mi][r] = -__builtin_inff();
      }
    }

    // per-lane max (no shuffles yet)
    float t0 = fmaxf(fmaxf(S[0][0], S[0][1]), fmaxf(S[0][2], S[0][3]));
    float t1 = fmaxf(fmaxf(S[1][0], S[1][1]), fmaxf(S[1][2], S[1][3]));
    float t2 = fmaxf(fmaxf(S[2][0], S[2][1]), fmaxf(S[2][2], S[2][3]));
    float t3 = fmaxf(fmaxf(S[3][0], S[3][1]), fmaxf(S[3][2], S[3][3]));
    float vloc = fmaxf(fmaxf(t0, t1), fmaxf(t2, t3));

    // defer-first: all-lanes check on LOCAL max == check on reduced max.
    // Wave-uniform -> no divergence. m_run==-inf (iter 0) -> false.
    float mnew = m_run;
    bool defer = __all(vloc - m_run <= 8.f) != 0;
    if (!defer) {
      float vmax = fmaxf(vloc, __shfl_xor(vloc, 16));
      vmax = fmaxf(vmax, __shfl_xor(vmax, 32));
      mnew = fmaxf(m_run, vmax);
      float alpha = __builtin_amdgcn_exp2f(m_run - mnew);
      m_run = mnew;
      l_part *= alpha;
      #pragma unroll
      for (int jd = 0; jd < 4; ++jd)
        #pragma unroll
        for (int r = 0; r < 4; ++r)
          Oacc[jd][r] *= alpha;
    }

    float rs = 0.f;
    #pragma unroll
    for (int mi = 0; mi < 4; ++mi) {
      float p0 = __builtin_amdgcn_exp2f(S[mi][0] - mnew);
      float p1 = __builtin_amdgcn_exp2f(S[mi][1] - mnew);
      float p2 = __builtin_amdgcn_exp2f(S[mi][2] - mnew);
      float p3 = __builtin_amdgcn_exp2f(S[mi][3] - mnew);
      rs += (p0 + p1) + (p2 + p3);
      uint2 pk;
      pk.x = pk2bf(p0, p1);
      pk.y = pk2bf(p2, p3);
      int gg = (2 * mi + (quad >> 1)) ^ swz;
      *(uint2*)&Ps[wave][l15 * 64 + gg * 8 + (quad & 1) * 4] = pk;
    }
    l_part += rs;                       // per-lane partial; reduced once at end

    if (kt < qt) {
      *(ushort8v*)&Kn[sdst] = kpre[0];
      *(ushort8v*)&Kn[sdst + 2048] = kpre[1];
      *(ushort8v*)&Vn[sdst] = vpre[0];
      *(ushort8v*)&Vn[sdst + 2048] = vpre[1];
    }

    __builtin_amdgcn_s_setprio(1);
    #pragma unroll
    for (int s = 0; s < 2; ++s) {
      short8 pf = *(const short8*)&Ps[wave][l15 * 64 + ((quad + 4 * s) ^ swz) * 8];
      #pragma unroll
      for (int jd = 0; jd < 4; ++jd) {
        short8 vfr = *(const short8*)&Vl[(jd * 16 + l15) * 64 + ((quad + 4 * s) ^ swz) * 8];
        Oacc[jd] = __builtin_amdgcn_mfma_f32_16x16x32_bf16(vfr, pf, Oacc[jd], 0, 0, 0);
      }
    }
    __builtin_amdgcn_s_setprio(0);
    if (kt < qt) __syncthreads();
  }

  // final denominator reduce (moved out of the loop: 2 shuffles total, was 2/iter)
  float l_run = l_part + __shfl_xor(l_part, 16);
  l_run += __shfl_xor(l_run, 32);

  // ---- fused out-projection epilogue (no barriers: each wave uses only its own Ps slot) ----
  {
    float linv = 1.f / l_run;
    unsigned short* Yl = &Ps[wave][0];
    #pragma unroll
    for (int jd = 0; jd < 4; ++jd) {
      uint2 pk;
      pk.x = pk2bf(Oacc[jd][0] * linv, Oacc[jd][1] * linv);
      pk.y = pk2bf(Oacc[jd][2] * linv, Oacc[jd][3] * linv);
      int gg = (jd * 2 + (quad >> 1)) ^ swz;
      *(uint2*)&Yl[l15 * 64 + gg * 8 + (quad & 1) * 4] = pk;
    }
    short8 wof[4][2];
    #pragma unroll
    for (int nt = 0; nt < 4; ++nt)
      #pragma unroll
      for (int s = 0; s < 2; ++s)
        wof[nt][s] = *(const short8*)(Wot + (size_t)(nt * 16 + l15) * 1024 + h * 64 + quad * 8 + 32 * s);
    f32x4 acc2[4] = {};
    #pragma unroll
    for (int s = 0; s < 2; ++s) {
      short8 ya = *(const short8*)&Yl[l15 * 64 + (((quad + 4 * s) ^ swz) * 8)];
      #pragma unroll
      for (int nt = 0; nt < 4; ++nt)
        acc2[nt] = __builtin_amdgcn_mfma_f32_16x16x32_bf16(ya, wof[nt][s], acc2[nt], 0, 0, 0);
    }
    int q0 = b * 2048 + qt * 64 + wave * 16 + quad * 4;
    #pragma unroll
    for (int nt = 0; nt < 4; ++nt)
      #pragma unroll
      for (int r = 0; r < 4; ++r)
        atomicAdd(&out[(size_t)(q0 + r) * 64 + nt * 16 + l15], acc2[nt][r]);
  }
}

// ---------------- launcher (3 kernels total) ----------------

extern "C" void kernel_launch(void* const* d_in, const int* in_sizes, int n_in,
                              void* d_out, int out_size, void* d_ws, size_t ws_size,
                              hipStream_t stream) {
  const float* x  = (const float*)d_in[0];
  const float* Wq = (const float*)d_in[1];
  const float* Wk = (const float*)d_in[2];
  const float* Wv = (const float*)d_in[3];
  const float* Wo = (const float*)d_in[4];
  const float* bo = (const float*)d_in[5];
  float* out = (float*)d_out;
  char* ws = (char*)d_ws;

  unsigned short* xb  = (unsigned short*)(ws);                       // 8 MB  [4096][1024]
  unsigned short* wqt = (unsigned short*)(ws + (8ull << 20));        // 2 MB Wq^T (head of contiguous [3072][1024] W-stack)
  unsigned short* wkt = (unsigned short*)(ws + (10ull << 20));       // 2 MB Wk^T (stack middle)
  unsigned short* wvt = (unsigned short*)(ws + (12ull << 20));       // 2 MB Wv^T (stack tail)
  unsigned short* wot = (unsigned short*)(ws + (14ull << 20));       // 128 KB Wo^T
  unsigned short* q   = (unsigned short*)(ws + (15ull << 20));       // 8 MB  [b][h][t][d]
  unsigned short* k   = (unsigned short*)(ws + (23ull << 20));       // 8 MB  [b][h][t][d]
  unsigned short* vt  = (unsigned short*)(ws + (31ull << 20));       // 8 MB  [b][h][d][t]

  prep<<<7488, 256, 0, stream>>>(x, Wq, Wk, Wv, Wo, bo, xb, wqt, wkt, wvt, wot, out);
  qkv_gemm3<<<768, 256, 0, stream>>>(xb, wqt, q, k, vt);
  attn14<<<dim3(32, 32), 256, 0, stream>>>(q, k, vt, wot, out);
}